// Round 1
// baseline (428.235 us; speedup 1.0000x reference)
//
#include <hip/hip_runtime.h>
#include <hip/hip_bf16.h>
#include <cstddef>

#define B 32
#define S 512
#define D 1536
#define D24 64
#define EPS 1e-5f

typedef float float4v __attribute__((ext_vector_type(4)));
typedef short short8 __attribute__((ext_vector_type(8)));

__device__ __forceinline__ float gelu_exact(float v) {
    return 0.5f * v * (1.0f + erff(v * 0.70710678118654752440f));
}

__device__ __forceinline__ unsigned short f2bf(float f) {
    union { float f; unsigned u; } x; x.f = f;
    unsigned r = x.u + 0x7fffu + ((x.u >> 16) & 1u);  // RNE
    return (unsigned short)(r >> 16);
}

// ---------------- Kernel 1: per-row LN stats (mu, rstd) ----------------
__global__ __launch_bounds__(256) void stats_kernel(const float* __restrict__ x,
                                                    float* __restrict__ stats) {
    const int row = blockIdx.x;             // b*S + s, 16384 rows
    const int tid = threadIdx.x;
    const float* xr = x + (size_t)row * D;
    float s1 = 0.f, s2 = 0.f;
    for (int j = tid; j < D; j += 256) { float v = xr[j]; s1 += v; s2 += v * v; }
    for (int off = 32; off > 0; off >>= 1) {
        s1 += __shfl_down(s1, off, 64);
        s2 += __shfl_down(s2, off, 64);
    }
    __shared__ float w1s[4], w2s[4];
    if ((tid & 63) == 0) { w1s[tid >> 6] = s1; w2s[tid >> 6] = s2; }
    __syncthreads();
    if (tid == 0) {
        s1 = w1s[0] + w1s[1] + w1s[2] + w1s[3];
        s2 = w2s[0] + w2s[1] + w2s[2] + w2s[3];
        float mu  = s1 * (1.0f / D);
        float var = s2 * (1.0f / D) - mu * mu;
        stats[row * 2 + 0] = mu;
        stats[row * 2 + 1] = rsqrtf(var + EPS);
    }
}

// ---------------- Kernel 2: convert Wi/Wii to bf16 ----------------
__global__ __launch_bounds__(256) void convw_kernel(const float* __restrict__ Wi,
                                                    const float* __restrict__ Wii,
                                                    unsigned short* __restrict__ wbf) {
    int i = blockIdx.x * 256 + threadIdx.x;   // grid covers 2*512*512
    float v = (i < S * S) ? Wi[i] : Wii[i - S * S];
    wbf[i] = f2bf(v);
}

// ------- Kernel 3: normalize + transpose to xnT[b][d][t] (bf16) + c slice (fp32) -------
__global__ __launch_bounds__(256) void nt_kernel(const float* __restrict__ x,
                                                 const float* __restrict__ stats,
                                                 const float* __restrict__ ln_g,
                                                 const float* __restrict__ ln_b,
                                                 unsigned short* __restrict__ xnT,
                                                 float* __restrict__ cbuf) {
    const int b  = blockIdx.z;
    const int t0 = blockIdx.y * 64;
    const int d0 = blockIdx.x * 64;
    const int tid = threadIdx.x;
    const int tx = tid & 63, ty = tid >> 6;
    __shared__ float tile[64][65];

    const float g  = ln_g[d0 + tx];
    const float bb = ln_b[d0 + tx];
    const bool write_c = (d0 == 0);

    for (int k = 0; k < 16; k++) {
        int row = ty + (k << 2);                       // t-offset in tile
        int grow = b * S + t0 + row;
        float mu   = stats[grow * 2 + 0];
        float rstd = stats[grow * 2 + 1];
        float v = x[(size_t)grow * D + d0 + tx];
        v = (v - mu) * rstd * g + bb;
        tile[row][tx] = v;
        if (write_c)
            cbuf[(size_t)(b * S + t0 + row) * D24 + tx] = v;
    }
    __syncthreads();
    for (int k = 0; k < 16; k++) {
        int drow = ty + (k << 2);                      // d-offset in tile
        float v = tile[tx][drow];                      // [t][d] -> transposed read
        xnT[((size_t)b * D + d0 + drow) * S + t0 + tx] = f2bf(v);
    }
}

// ---------------- Kernel 4: gating MLP -> sel[b] in {0,1} ----------------
__global__ __launch_bounds__(256) void gate_kernel(const float* __restrict__ cbuf,
                                                   const float* __restrict__ w1,
                                                   const float* __restrict__ b1,
                                                   const float* __restrict__ wc,
                                                   const float* __restrict__ bc,
                                                   const float* __restrict__ w2,
                                                   const float* __restrict__ b2,
                                                   int* __restrict__ sel) {
    const int b = blockIdx.x;
    const int tid = threadIdx.x;
    __shared__ float w1s[D24 * 10];
    __shared__ float red[10 * 256];
    for (int i = tid; i < D24 * 10; i += 256) w1s[i] = w1[i];
    __syncthreads();

    float acc[10];
#pragma unroll
    for (int k = 0; k < 10; k++) acc[k] = 0.f;

    for (int s = tid; s < S; s += 256) {
        const float* cr = cbuf + ((size_t)b * S + s) * D24;
        float cv[D24];
#pragma unroll
        for (int i = 0; i < 16; i++) {
            float4 t4 = *(const float4*)(cr + i * 4);
            cv[i * 4 + 0] = t4.x; cv[i * 4 + 1] = t4.y;
            cv[i * 4 + 2] = t4.z; cv[i * 4 + 3] = t4.w;
        }
        float wcs = wc[s];
#pragma unroll
        for (int k = 0; k < 10; k++) {
            float d = b1[k];
#pragma unroll
            for (int i = 0; i < D24; i++) d += cv[i] * w1s[i * 10 + k];
            acc[k] += gelu_exact(d) * wcs;
        }
    }
#pragma unroll
    for (int k = 0; k < 10; k++) red[k * 256 + tid] = acc[k];
    __syncthreads();
    for (int off = 128; off > 0; off >>= 1) {
        if (tid < off)
#pragma unroll
            for (int k = 0; k < 10; k++)
                red[k * 256 + tid] += red[k * 256 + tid + off];
        __syncthreads();
    }
    if (tid == 0) {
        float logit = b2[0];
#pragma unroll
        for (int k = 0; k < 10; k++)
            logit += gelu_exact(red[k * 256] + bc[0]) * w2[k];
        // sigmoid(logit) >= 0.5  <=>  logit >= 0  =>  round -> 1
        sel[b] = (logit >= 0.f) ? 1 : 0;
    }
}

// ---------------- Kernel 5: main GEMM + bias + residual + gelu ----------------
// out[b,s,d] = gelu( sum_t W[s,t]*xn[b,t,d] + bias[s] + x[b,s,d] )
// A = W (bf16, row-major s x t), B = xnT[b] (bf16, row-major d x t) -> both K-major.
__global__ __launch_bounds__(256, 2) void gemm_kernel(const unsigned short* __restrict__ xnT,
                                                      const unsigned short* __restrict__ wbf,
                                                      const int* __restrict__ sel,
                                                      const float* __restrict__ bi,
                                                      const float* __restrict__ bii,
                                                      const float* __restrict__ x,
                                                      float* __restrict__ out) {
    const int b  = blockIdx.z;
    const int s0 = blockIdx.y * 128;
    const int d0 = blockIdx.x * 128;
    const int tid  = threadIdx.x;
    const int lane = tid & 63;
    const int wid  = tid >> 6;
    const int wm = (wid & 1) * 64;
    const int wn = (wid >> 1) * 64;
    const int q   = lane >> 4;
    const int r16 = lane & 15;

    const int ssel = sel[b];
    const unsigned short* W = wbf + (size_t)ssel * S * S;
    const float* bias = ssel ? bii : bi;
    const unsigned short* Xb = xnT + (size_t)b * D * S;

    // K-outer chunk layout: element (row, k) at [(k/8)*128 + row]*8 + (k%8)
    __shared__ __align__(16) unsigned short As[128 * 32];
    __shared__ __align__(16) unsigned short Bs[128 * 32];

    float4v acc[4][4];
#pragma unroll
    for (int mi = 0; mi < 4; mi++)
#pragma unroll
        for (int ni = 0; ni < 4; ni++) acc[mi][ni] = (float4v){0.f, 0.f, 0.f, 0.f};

    for (int k0 = 0; k0 < S; k0 += 32) {
#pragma unroll
        for (int j = 0; j < 2; j++) {
            int chunk = tid + (j << 8);         // 0..511
            int row = chunk >> 2;               // 0..127
            int c16 = chunk & 3;                // 16B chunk within the 32-wide k
            short8 av = *(const short8*)(W  + (size_t)(s0 + row) * S + k0 + c16 * 8);
            short8 bv = *(const short8*)(Xb + (size_t)(d0 + row) * S + k0 + c16 * 8);
            *(short8*)(As + (c16 * 128 + row) * 8) = av;
            *(short8*)(Bs + (c16 * 128 + row) * 8) = bv;
        }
        __syncthreads();

        short8 af[4], bfr[4];
#pragma unroll
        for (int mi = 0; mi < 4; mi++)
            af[mi] = *(const short8*)(As + (q * 128 + wm + mi * 16 + r16) * 8);
#pragma unroll
        for (int ni = 0; ni < 4; ni++)
            bfr[ni] = *(const short8*)(Bs + (q * 128 + wn + ni * 16 + r16) * 8);
#pragma unroll
        for (int mi = 0; mi < 4; mi++)
#pragma unroll
            for (int ni = 0; ni < 4; ni++)
                acc[mi][ni] = __builtin_amdgcn_mfma_f32_16x16x32_bf16(
                    af[mi], bfr[ni], acc[mi][ni], 0, 0, 0);
        __syncthreads();
    }

    // Epilogue: C/D layout col=lane&15, row=(lane>>4)*4+r
#pragma unroll
    for (int mi = 0; mi < 4; mi++) {
        int srow = s0 + wm + mi * 16 + q * 4;
#pragma unroll
        for (int ni = 0; ni < 4; ni++) {
            int d = d0 + wn + ni * 16 + r16;
#pragma unroll
            for (int r = 0; r < 4; r++) {
                int ss = srow + r;
                size_t gi = ((size_t)b * S + ss) * D + d;
                float v = acc[mi][ni][r] + bias[ss] + x[gi];
                out[gi] = gelu_exact(v);
            }
        }
    }
}

extern "C" void kernel_launch(void* const* d_in, const int* in_sizes, int n_in,
                              void* d_out, int out_size, void* d_ws, size_t ws_size,
                              hipStream_t stream) {
    const float* x    = (const float*)d_in[0];
    const float* ln_g = (const float*)d_in[1];
    const float* ln_b = (const float*)d_in[2];
    const float* w1   = (const float*)d_in[3];
    const float* b1   = (const float*)d_in[4];
    const float* wc   = (const float*)d_in[5];
    const float* bc   = (const float*)d_in[6];
    const float* w2   = (const float*)d_in[7];
    const float* b2   = (const float*)d_in[8];
    const float* Wi   = (const float*)d_in[9];
    const float* bi   = (const float*)d_in[10];
    const float* Wii  = (const float*)d_in[11];
    const float* bii  = (const float*)d_in[12];
    float* out = (float*)d_out;

    char* ws = (char*)d_ws;
    const size_t XNT_BYTES   = (size_t)B * D * S * 2;        // 50331648
    const size_t STATS_BYTES = (size_t)B * S * 2 * 4;        // 131072
    const size_t C_BYTES     = (size_t)B * S * D24 * 4;      // 4194304
    const size_t WBF_BYTES   = (size_t)2 * S * S * 2;        // 1048576
    unsigned short* xnT  = (unsigned short*)ws;
    float*          stat = (float*)(ws + XNT_BYTES);
    float*          cbuf = (float*)(ws + XNT_BYTES + STATS_BYTES);
    unsigned short* wbf  = (unsigned short*)(ws + XNT_BYTES + STATS_BYTES + C_BYTES);
    int*            sel  = (int*)(ws + XNT_BYTES + STATS_BYTES + C_BYTES + WBF_BYTES);

    stats_kernel<<<B * S, 256, 0, stream>>>(x, stat);
    convw_kernel<<<(2 * S * S) / 256, 256, 0, stream>>>(Wi, Wii, wbf);
    nt_kernel<<<dim3(D / 64, S / 64, B), 256, 0, stream>>>(x, stat, ln_g, ln_b, xnT, cbuf);
    gate_kernel<<<B, 256, 0, stream>>>(cbuf, w1, b1, wc, bc, w2, b2, sel);
    gemm_kernel<<<dim3(D / 128, S / 128, B), 256, 0, stream>>>(xnT, wbf, sel, bi, bii, x, out);
}

// Round 2
// 314.992 us; speedup vs baseline: 1.3595x; 1.3595x over previous
//
#include <hip/hip_runtime.h>
#include <hip/hip_bf16.h>
#include <cstddef>

#define B 32
#define S 512
#define D 1536
#define D24 64
#define EPS 1e-5f

typedef float float4v __attribute__((ext_vector_type(4)));
typedef short short8 __attribute__((ext_vector_type(8)));

__device__ __forceinline__ float gelu_exact(float v) {
    return 0.5f * v * (1.0f + erff(v * 0.70710678118654752440f));
}

__device__ __forceinline__ unsigned short f2bf(float f) {
    union { float f; unsigned u; } x; x.f = f;
    unsigned r = x.u + 0x7fffu + ((x.u >> 16) & 1u);  // RNE
    return (unsigned short)(r >> 16);
}

// ---------------- Kernel 1: per-row LN stats (mu, rstd); one wave per row ----------------
__global__ __launch_bounds__(256) void stats_kernel(const float* __restrict__ x,
                                                    float* __restrict__ stats) {
    const int lane = threadIdx.x & 63;
    const int w    = threadIdx.x >> 6;
    const int row  = blockIdx.x * 4 + w;            // 4096 blocks x 4 waves
    const float4* xr = (const float4*)(x + (size_t)row * D);   // 384 float4
    float s1 = 0.f, s2 = 0.f;
#pragma unroll
    for (int j = 0; j < 6; j++) {
        float4 v = xr[lane + j * 64];
        s1 += v.x + v.y + v.z + v.w;
        s2 += v.x * v.x + v.y * v.y + v.z * v.z + v.w * v.w;
    }
#pragma unroll
    for (int off = 32; off > 0; off >>= 1) {
        s1 += __shfl_down(s1, off, 64);
        s2 += __shfl_down(s2, off, 64);
    }
    if (lane == 0) {
        float mu  = s1 * (1.0f / D);
        float var = s2 * (1.0f / D) - mu * mu;
        stats[row * 2 + 0] = mu;
        stats[row * 2 + 1] = rsqrtf(var + EPS);
    }
}

// ---------------- Kernel 2: convert Wi/Wii to bf16 (vectorized) ----------------
__global__ __launch_bounds__(256) void convw_kernel(const float* __restrict__ Wi,
                                                    const float* __restrict__ Wii,
                                                    unsigned short* __restrict__ wbf) {
    int i = (blockIdx.x * 256 + threadIdx.x) * 4;   // grid covers 2*512*512 floats
    const float* src = (i < S * S) ? (Wi + i) : (Wii + i - S * S);
    float4 v = *(const float4*)src;
    unsigned short o[4] = {f2bf(v.x), f2bf(v.y), f2bf(v.z), f2bf(v.w)};
    *(uint2*)(wbf + i) = *(const uint2*)o;
}

// ------- Kernel 3: normalize + transpose to xnT[b][d][t] (bf16) + transposed c slice (fp32) -------
__global__ __launch_bounds__(256) void nt_kernel(const float* __restrict__ x,
                                                 const float* __restrict__ stats,
                                                 const float* __restrict__ ln_g,
                                                 const float* __restrict__ ln_b,
                                                 unsigned short* __restrict__ xnT,
                                                 float* __restrict__ cbufT) {
    const int b  = blockIdx.z;
    const int t0 = blockIdx.y * 64;
    const int d0 = blockIdx.x * 64;
    const int tid = threadIdx.x;
    __shared__ float tile[64][65];                 // [t][d]

    // phase 1: coalesced float4 reads of x, normalize, store [t][d]
    const int dq = (tid & 15) * 4;
    const int rg = tid >> 4;                       // 0..15
    float4 g4 = *(const float4*)(ln_g + d0 + dq);
    float4 b4 = *(const float4*)(ln_b + d0 + dq);
#pragma unroll
    for (int p = 0; p < 4; p++) {
        int row  = rg + p * 16;
        int grow = b * S + t0 + row;
        float mu   = stats[grow * 2 + 0];
        float rstd = stats[grow * 2 + 1];
        float4 v = *(const float4*)(x + (size_t)grow * D + d0 + dq);
        tile[row][dq + 0] = (v.x - mu) * rstd * g4.x + b4.x;
        tile[row][dq + 1] = (v.y - mu) * rstd * g4.y + b4.y;
        tile[row][dq + 2] = (v.z - mu) * rstd * g4.z + b4.z;
        tile[row][dq + 3] = (v.w - mu) * rstd * g4.w + b4.w;
    }
    __syncthreads();

    // phase 2: transposed 16B writes
    const int t8  = (tid & 7) * 8;
    const int dr0 = tid >> 3;                      // 0..31
    const bool write_c = (d0 == 0);
#pragma unroll
    for (int p = 0; p < 2; p++) {
        int drow = dr0 + p * 32;
        float fv[8];
        unsigned short bv[8];
#pragma unroll
        for (int j = 0; j < 8; j++) { fv[j] = tile[t8 + j][drow]; bv[j] = f2bf(fv[j]); }
        *(short8*)(xnT + ((size_t)b * D + d0 + drow) * S + t0 + t8) = *(const short8*)bv;
        if (write_c) {
            float* cp = cbufT + ((size_t)b * D24 + drow) * S + t0 + t8;
            *(float4*)(cp + 0) = (float4){fv[0], fv[1], fv[2], fv[3]};
            *(float4*)(cp + 4) = (float4){fv[4], fv[5], fv[6], fv[7]};
        }
    }
}

// ---------------- Kernel 4a: gating MLP stage A (coalesced over s) ----------------
__global__ __launch_bounds__(256) void gateA_kernel(const float* __restrict__ cbufT,
                                                    const float* __restrict__ w1,
                                                    const float* __restrict__ b1,
                                                    const float* __restrict__ wc,
                                                    float* __restrict__ partial) {
    const int b  = blockIdx.x >> 1;
    const int sb = blockIdx.x & 1;
    const int tid = threadIdx.x;
    const int s = sb * 256 + tid;
    __shared__ float w1s[D24 * 10];
    __shared__ float wsum[4][10];
    for (int i = tid; i < D24 * 10; i += 256) w1s[i] = w1[i];
    __syncthreads();

    float acc[10];
#pragma unroll
    for (int k = 0; k < 10; k++) acc[k] = b1[k];
    const float* cb = cbufT + (size_t)b * D24 * S + s;
#pragma unroll 8
    for (int i = 0; i < D24; i++) {
        float v = cb[(size_t)i * S];
#pragma unroll
        for (int k = 0; k < 10; k++) acc[k] += v * w1s[i * 10 + k];
    }
    float wcs = wc[s];
#pragma unroll
    for (int k = 0; k < 10; k++) {
        float t = gelu_exact(acc[k]) * wcs;
#pragma unroll
        for (int off = 32; off > 0; off >>= 1) t += __shfl_down(t, off, 64);
        if ((tid & 63) == 0) wsum[tid >> 6][k] = t;
    }
    __syncthreads();
    if (tid < 10)
        partial[blockIdx.x * 10 + tid] =
            wsum[0][tid] + wsum[1][tid] + wsum[2][tid] + wsum[3][tid];
}

// ---------------- Kernel 4b: gating MLP stage B -> sel[b] ----------------
__global__ __launch_bounds__(64) void gateB_kernel(const float* __restrict__ partial,
                                                   const float* __restrict__ wc_dummy,
                                                   const float* __restrict__ bc,
                                                   const float* __restrict__ w2,
                                                   const float* __restrict__ b2,
                                                   int* __restrict__ sel) {
    int b = threadIdx.x;
    if (b < B) {
        float logit = b2[0];
        float bc0 = bc[0];
#pragma unroll
        for (int k = 0; k < 10; k++) {
            float ssum = partial[(b * 2) * 10 + k] + partial[(b * 2 + 1) * 10 + k];
            logit += gelu_exact(ssum + bc0) * w2[k];
        }
        sel[b] = (logit >= 0.f) ? 1 : 0;   // round(sigmoid(x)) == (x >= 0)
    }
}

// ---------------- Kernel 5: main GEMM + bias + residual + gelu ----------------
// out[b,s,d] = gelu( sum_t W[s,t]*xn[b,t,d] + bias[s] + x[b,s,d] )
// A = W (bf16, s x t row-major), B = xnT[b] (bf16, d x t row-major) -> both K-major.
// LDS: row-major [row][32 k] tiles, filled via global_load_lds (lane-contiguous order).
__global__ __launch_bounds__(256) void gemm_kernel(const unsigned short* __restrict__ xnT,
                                                   const unsigned short* __restrict__ wbf,
                                                   const int* __restrict__ sel,
                                                   const float* __restrict__ bi,
                                                   const float* __restrict__ bii,
                                                   const float* __restrict__ x,
                                                   float* __restrict__ out) {
    const int b  = blockIdx.z;
    const int s0 = blockIdx.y * 128;
    const int d0 = blockIdx.x * 128;
    const int tid  = threadIdx.x;
    const int lane = tid & 63;
    const int wid  = tid >> 6;
    const int wm = (wid & 1) * 64;
    const int wn = (wid >> 1) * 64;
    const int q   = lane >> 4;
    const int r16 = lane & 15;

    const int ssel = sel[b];
    const unsigned short* W = wbf + (size_t)ssel * S * S;
    const float* bias = ssel ? bii : bi;
    const unsigned short* Xb = xnT + (size_t)b * D * S;

    __shared__ __align__(16) unsigned short As[128 * 32];  // [row][k]
    __shared__ __align__(16) unsigned short Bs[128 * 32];

    float4v acc[4][4];
#pragma unroll
    for (int mi = 0; mi < 4; mi++)
#pragma unroll
        for (int ni = 0; ni < 4; ni++) acc[mi][ni] = (float4v){0.f, 0.f, 0.f, 0.f};

    for (int k0 = 0; k0 < S; k0 += 32) {
        // async stage: chunk c = i*256 + wid*64 + lane; row = c>>2, k-chunk = c&3
#pragma unroll
        for (int i = 0; i < 2; i++) {
            int c = i * 256 + wid * 64 + lane;
            int row = c >> 2, c16 = c & 3;
            const unsigned short* gaA = W  + (size_t)(s0 + row) * S + k0 + c16 * 8;
            const unsigned short* gaB = Xb + (size_t)(d0 + row) * S + k0 + c16 * 8;
            unsigned short* laA = As + (size_t)(i * 256 + wid * 64) * 8;  // wave-uniform base
            unsigned short* laB = Bs + (size_t)(i * 256 + wid * 64) * 8;
            __builtin_amdgcn_global_load_lds(
                (const __attribute__((address_space(1))) void*)gaA,
                (__attribute__((address_space(3))) void*)laA, 16, 0, 0);
            __builtin_amdgcn_global_load_lds(
                (const __attribute__((address_space(1))) void*)gaB,
                (__attribute__((address_space(3))) void*)laB, 16, 0, 0);
        }
        __syncthreads();

        short8 af[4], bfr[4];
#pragma unroll
        for (int mi = 0; mi < 4; mi++)
            af[mi] = *(const short8*)(As + (wm + mi * 16 + r16) * 32 + q * 8);
#pragma unroll
        for (int ni = 0; ni < 4; ni++)
            bfr[ni] = *(const short8*)(Bs + (wn + ni * 16 + r16) * 32 + q * 8);
#pragma unroll
        for (int mi = 0; mi < 4; mi++)
#pragma unroll
            for (int ni = 0; ni < 4; ni++)
                acc[mi][ni] = __builtin_amdgcn_mfma_f32_16x16x32_bf16(
                    af[mi], bfr[ni], acc[mi][ni], 0, 0, 0);
        __syncthreads();
    }

    // Epilogue: C/D layout col=lane&15, row=(lane>>4)*4+r
#pragma unroll
    for (int mi = 0; mi < 4; mi++) {
        int srow = s0 + wm + mi * 16 + q * 4;
#pragma unroll
        for (int ni = 0; ni < 4; ni++) {
            int d = d0 + wn + ni * 16 + r16;
#pragma unroll
            for (int r = 0; r < 4; r++) {
                int ss = srow + r;
                size_t gi = ((size_t)b * S + ss) * D + d;
                float v = acc[mi][ni][r] + bias[ss] + x[gi];
                out[gi] = gelu_exact(v);
            }
        }
    }
}

extern "C" void kernel_launch(void* const* d_in, const int* in_sizes, int n_in,
                              void* d_out, int out_size, void* d_ws, size_t ws_size,
                              hipStream_t stream) {
    const float* x    = (const float*)d_in[0];
    const float* ln_g = (const float*)d_in[1];
    const float* ln_b = (const float*)d_in[2];
    const float* w1   = (const float*)d_in[3];
    const float* b1   = (const float*)d_in[4];
    const float* wc   = (const float*)d_in[5];
    const float* bc   = (const float*)d_in[6];
    const float* w2   = (const float*)d_in[7];
    const float* b2   = (const float*)d_in[8];
    const float* Wi   = (const float*)d_in[9];
    const float* bi   = (const float*)d_in[10];
    const float* Wii  = (const float*)d_in[11];
    const float* bii  = (const float*)d_in[12];
    float* out = (float*)d_out;

    char* ws = (char*)d_ws;
    const size_t XNT_BYTES   = (size_t)B * D * S * 2;        // 50331648
    const size_t STATS_BYTES = (size_t)B * S * 2 * 4;        // 131072
    const size_t C_BYTES     = (size_t)B * D24 * S * 4;      // 4194304 (transposed)
    const size_t WBF_BYTES   = (size_t)2 * S * S * 2;        // 1048576
    const size_t PART_BYTES  = (size_t)B * 2 * 10 * 4;       // 2560
    unsigned short* xnT   = (unsigned short*)ws;
    float*          stat  = (float*)(ws + XNT_BYTES);
    float*          cbufT = (float*)(ws + XNT_BYTES + STATS_BYTES);
    unsigned short* wbf   = (unsigned short*)(ws + XNT_BYTES + STATS_BYTES + C_BYTES);
    float*          part  = (float*)(ws + XNT_BYTES + STATS_BYTES + C_BYTES + WBF_BYTES);
    int*            sel   = (int*)(ws + XNT_BYTES + STATS_BYTES + C_BYTES + WBF_BYTES + PART_BYTES);

    stats_kernel<<<(B * S) / 4, 256, 0, stream>>>(x, stat);
    convw_kernel<<<(2 * S * S) / 1024, 256, 0, stream>>>(Wi, Wii, wbf);
    nt_kernel<<<dim3(D / 64, S / 64, B), 256, 0, stream>>>(x, stat, ln_g, ln_b, xnT, cbufT);
    gateA_kernel<<<B * 2, 256, 0, stream>>>(cbufT, w1, b1, wc, part);
    gateB_kernel<<<1, 64, 0, stream>>>(part, wc, bc, w2, b2, sel);
    gemm_kernel<<<dim3(D / 128, S / 128, B), 256, 0, stream>>>(xnT, wbf, sel, bi, bii, x, out);
}

// Round 3
// 305.641 us; speedup vs baseline: 1.4011x; 1.0306x over previous
//
#include <hip/hip_runtime.h>
#include <hip/hip_bf16.h>
#include <cstddef>

#define B 32
#define S 512
#define D 1536
#define D24 64
#define EPS 1e-5f

typedef float float4v __attribute__((ext_vector_type(4)));
typedef short short8 __attribute__((ext_vector_type(8)));

__device__ __forceinline__ float gelu_exact(float v) {
    return 0.5f * v * (1.0f + erff(v * 0.70710678118654752440f));
}

// tanh-form gelu: 0.5x(1+tanh(0.79788456(x+0.044715x^3))) == x*sigmoid(1.59577(x+0.044715x^3))
// max abs error vs exact ~1e-3, far below the 0.164 threshold. Used ONLY in the epilogue.
__device__ __forceinline__ float gelu_fast(float v) {
    float u = v * v;
    float z = v * __builtin_fmaf(0.07135481627f, u, 1.5957691216f);
    return v / (1.0f + __expf(-z));
}

__device__ __forceinline__ unsigned short f2bf(float f) {
    union { float f; unsigned u; } x; x.f = f;
    unsigned r = x.u + 0x7fffu + ((x.u >> 16) & 1u);  // RNE
    return (unsigned short)(r >> 16);
}

// ---------------- Kernel 1: per-row LN stats (mu, rstd); one wave per row ----------------
__global__ __launch_bounds__(256) void stats_kernel(const float* __restrict__ x,
                                                    float* __restrict__ stats) {
    const int lane = threadIdx.x & 63;
    const int w    = threadIdx.x >> 6;
    const int row  = blockIdx.x * 4 + w;            // 4096 blocks x 4 waves
    const float4* xr = (const float4*)(x + (size_t)row * D);   // 384 float4
    float s1 = 0.f, s2 = 0.f;
#pragma unroll
    for (int j = 0; j < 6; j++) {
        float4 v = xr[lane + j * 64];
        s1 += v.x + v.y + v.z + v.w;
        s2 += v.x * v.x + v.y * v.y + v.z * v.z + v.w * v.w;
    }
#pragma unroll
    for (int off = 32; off > 0; off >>= 1) {
        s1 += __shfl_down(s1, off, 64);
        s2 += __shfl_down(s2, off, 64);
    }
    if (lane == 0) {
        float mu  = s1 * (1.0f / D);
        float var = s2 * (1.0f / D) - mu * mu;
        stats[row * 2 + 0] = mu;
        stats[row * 2 + 1] = rsqrtf(var + EPS);
    }
}

// ---------------- Kernel 2: convert Wi/Wii to bf16 (vectorized) ----------------
__global__ __launch_bounds__(256) void convw_kernel(const float* __restrict__ Wi,
                                                    const float* __restrict__ Wii,
                                                    unsigned short* __restrict__ wbf) {
    int i = (blockIdx.x * 256 + threadIdx.x) * 4;   // grid covers 2*512*512 floats
    const float* src = (i < S * S) ? (Wi + i) : (Wii + i - S * S);
    float4 v = *(const float4*)src;
    unsigned short o[4] = {f2bf(v.x), f2bf(v.y), f2bf(v.z), f2bf(v.w)};
    *(uint2*)(wbf + i) = *(const uint2*)o;
}

// ------- Kernel 3: normalize + transpose to xnT[b][d][t] (bf16) + transposed c slice (fp32) -------
__global__ __launch_bounds__(256) void nt_kernel(const float* __restrict__ x,
                                                 const float* __restrict__ stats,
                                                 const float* __restrict__ ln_g,
                                                 const float* __restrict__ ln_b,
                                                 unsigned short* __restrict__ xnT,
                                                 float* __restrict__ cbufT) {
    const int b  = blockIdx.z;
    const int t0 = blockIdx.y * 64;
    const int d0 = blockIdx.x * 64;
    const int tid = threadIdx.x;
    __shared__ float tile[64][65];                 // [t][d]

    // phase 1: coalesced float4 reads of x, normalize, store [t][d]
    const int dq = (tid & 15) * 4;
    const int rg = tid >> 4;                       // 0..15
    float4 g4 = *(const float4*)(ln_g + d0 + dq);
    float4 b4 = *(const float4*)(ln_b + d0 + dq);
#pragma unroll
    for (int p = 0; p < 4; p++) {
        int row  = rg + p * 16;
        int grow = b * S + t0 + row;
        float mu   = stats[grow * 2 + 0];
        float rstd = stats[grow * 2 + 1];
        float4 v = *(const float4*)(x + (size_t)grow * D + d0 + dq);
        tile[row][dq + 0] = (v.x - mu) * rstd * g4.x + b4.x;
        tile[row][dq + 1] = (v.y - mu) * rstd * g4.y + b4.y;
        tile[row][dq + 2] = (v.z - mu) * rstd * g4.z + b4.z;
        tile[row][dq + 3] = (v.w - mu) * rstd * g4.w + b4.w;
    }
    __syncthreads();

    // phase 2: transposed 16B writes
    const int t8  = (tid & 7) * 8;
    const int dr0 = tid >> 3;                      // 0..31
    const bool write_c = (d0 == 0);
#pragma unroll
    for (int p = 0; p < 2; p++) {
        int drow = dr0 + p * 32;
        float fv[8];
        unsigned short bv[8];
#pragma unroll
        for (int j = 0; j < 8; j++) { fv[j] = tile[t8 + j][drow]; bv[j] = f2bf(fv[j]); }
        *(short8*)(xnT + ((size_t)b * D + d0 + drow) * S + t0 + t8) = *(const short8*)bv;
        if (write_c) {
            float* cp = cbufT + ((size_t)b * D24 + drow) * S + t0 + t8;
            *(float4*)(cp + 0) = (float4){fv[0], fv[1], fv[2], fv[3]};
            *(float4*)(cp + 4) = (float4){fv[4], fv[5], fv[6], fv[7]};
        }
    }
}

// ---------------- Kernel 4a: gating MLP stage A (coalesced over s) ----------------
__global__ __launch_bounds__(256) void gateA_kernel(const float* __restrict__ cbufT,
                                                    const float* __restrict__ w1,
                                                    const float* __restrict__ b1,
                                                    const float* __restrict__ wc,
                                                    float* __restrict__ partial) {
    const int b  = blockIdx.x >> 1;
    const int sb = blockIdx.x & 1;
    const int tid = threadIdx.x;
    const int s = sb * 256 + tid;
    __shared__ float w1s[D24 * 10];
    __shared__ float wsum[4][10];
    for (int i = tid; i < D24 * 10; i += 256) w1s[i] = w1[i];
    __syncthreads();

    float acc[10];
#pragma unroll
    for (int k = 0; k < 10; k++) acc[k] = b1[k];
    const float* cb = cbufT + (size_t)b * D24 * S + s;
#pragma unroll 8
    for (int i = 0; i < D24; i++) {
        float v = cb[(size_t)i * S];
#pragma unroll
        for (int k = 0; k < 10; k++) acc[k] += v * w1s[i * 10 + k];
    }
    float wcs = wc[s];
#pragma unroll
    for (int k = 0; k < 10; k++) {
        float t = gelu_exact(acc[k]) * wcs;
#pragma unroll
        for (int off = 32; off > 0; off >>= 1) t += __shfl_down(t, off, 64);
        if ((tid & 63) == 0) wsum[tid >> 6][k] = t;
    }
    __syncthreads();
    if (tid < 10)
        partial[blockIdx.x * 10 + tid] =
            wsum[0][tid] + wsum[1][tid] + wsum[2][tid] + wsum[3][tid];
}

// ---------------- Kernel 4b: gating MLP stage B -> sel[b] ----------------
__global__ __launch_bounds__(64) void gateB_kernel(const float* __restrict__ partial,
                                                   const float* __restrict__ bc,
                                                   const float* __restrict__ w2,
                                                   const float* __restrict__ b2,
                                                   int* __restrict__ sel) {
    int b = threadIdx.x;
    if (b < B) {
        float logit = b2[0];
        float bc0 = bc[0];
#pragma unroll
        for (int k = 0; k < 10; k++) {
            float ssum = partial[(b * 2) * 10 + k] + partial[(b * 2 + 1) * 10 + k];
            logit += gelu_exact(ssum + bc0) * w2[k];
        }
        sel[b] = (logit >= 0.f) ? 1 : 0;   // round(sigmoid(x)) == (x >= 0)
    }
}

// ---------------- Kernel 5: main GEMM + bias + residual + gelu ----------------
// out[b,s,d] = gelu( sum_t W[s,t]*xn[b,t,d] + bias[s] + x[b,s,d] )
// A = W (bf16, s x t row-major), B = xnT[b] (bf16, d x t row-major) -> both K-major.
// BK=64, LDS 16B chunks XOR-swizzled: chunk c of row stored at slot c^(row&7).
// global_load_lds keeps lane-linear LDS targets; the *global* address is permuted.
__global__ __launch_bounds__(256, 4) void gemm_kernel(const unsigned short* __restrict__ xnT,
                                                      const unsigned short* __restrict__ wbf,
                                                      const int* __restrict__ sel,
                                                      const float* __restrict__ bi,
                                                      const float* __restrict__ bii,
                                                      const float* __restrict__ x,
                                                      float* __restrict__ out) {
    const int b  = blockIdx.z;
    const int s0 = blockIdx.y * 128;
    const int d0 = blockIdx.x * 128;
    const int tid  = threadIdx.x;
    const int lane = tid & 63;
    const int wid  = tid >> 6;
    const int wm = (wid & 1) * 64;
    const int wn = (wid >> 1) * 64;
    const int q   = lane >> 4;
    const int r16 = lane & 15;

    const int ssel = sel[b];
    const unsigned short* W = wbf + (size_t)ssel * S * S;
    const float* bias = ssel ? bii : bi;
    const unsigned short* Xb = xnT + (size_t)b * D * S;

    __shared__ __align__(16) unsigned short As[128 * 64];  // [row][64k], swizzled chunks
    __shared__ __align__(16) unsigned short Bs[128 * 64];

    float4v acc[4][4];
#pragma unroll
    for (int mi = 0; mi < 4; mi++)
#pragma unroll
        for (int ni = 0; ni < 4; ni++) acc[mi][ni] = (float4v){0.f, 0.f, 0.f, 0.f};

    for (int k0 = 0; k0 < S; k0 += 64) {
        // stage 128x64 of A and B: 4 instrs each, lane-linear LDS, swizzled global chunk
#pragma unroll
        for (int i = 0; i < 4; i++) {
            int L = i * 256 + tid;          // LDS 16B-chunk index 0..1023
            int row = L >> 3;               // 0..127
            int sc  = L & 7;                // stored chunk slot
            int c16 = sc ^ (row & 7);       // logical k-chunk held in that slot
            const unsigned short* gaA = W  + (size_t)(s0 + row) * S + k0 + c16 * 8;
            const unsigned short* gaB = Xb + (size_t)(d0 + row) * S + k0 + c16 * 8;
            unsigned short* laA = As + (size_t)(i * 256 + wid * 64) * 8;  // wave-uniform base
            unsigned short* laB = Bs + (size_t)(i * 256 + wid * 64) * 8;
            __builtin_amdgcn_global_load_lds(
                (const __attribute__((address_space(1))) void*)gaA,
                (__attribute__((address_space(3))) void*)laA, 16, 0, 0);
            __builtin_amdgcn_global_load_lds(
                (const __attribute__((address_space(1))) void*)gaB,
                (__attribute__((address_space(3))) void*)laB, 16, 0, 0);
        }
        __syncthreads();

#pragma unroll
        for (int h = 0; h < 2; h++) {
            short8 af[4], bfr[4];
#pragma unroll
            for (int mi = 0; mi < 4; mi++) {
                int row = wm + mi * 16 + r16;
                af[mi] = *(const short8*)(As + row * 64 + (((h << 2) + q) ^ (r16 & 7)) * 8);
            }
#pragma unroll
            for (int ni = 0; ni < 4; ni++) {
                int row = wn + ni * 16 + r16;
                bfr[ni] = *(const short8*)(Bs + row * 64 + (((h << 2) + q) ^ (r16 & 7)) * 8);
            }
#pragma unroll
            for (int mi = 0; mi < 4; mi++)
#pragma unroll
                for (int ni = 0; ni < 4; ni++)
                    acc[mi][ni] = __builtin_amdgcn_mfma_f32_16x16x32_bf16(
                        af[mi], bfr[ni], acc[mi][ni], 0, 0, 0);
        }
        __syncthreads();
    }

    // Epilogue: C/D layout col=lane&15, row=(lane>>4)*4+r ; fast gelu
#pragma unroll
    for (int mi = 0; mi < 4; mi++) {
        int srow = s0 + wm + mi * 16 + q * 4;
#pragma unroll
        for (int ni = 0; ni < 4; ni++) {
            int d = d0 + wn + ni * 16 + r16;
#pragma unroll
            for (int r = 0; r < 4; r++) {
                int ss = srow + r;
                size_t gi = ((size_t)b * S + ss) * D + d;
                float v = acc[mi][ni][r] + bias[ss] + x[gi];
                out[gi] = gelu_fast(v);
            }
        }
    }
}

extern "C" void kernel_launch(void* const* d_in, const int* in_sizes, int n_in,
                              void* d_out, int out_size, void* d_ws, size_t ws_size,
                              hipStream_t stream) {
    const float* x    = (const float*)d_in[0];
    const float* ln_g = (const float*)d_in[1];
    const float* ln_b = (const float*)d_in[2];
    const float* w1   = (const float*)d_in[3];
    const float* b1   = (const float*)d_in[4];
    const float* wc   = (const float*)d_in[5];
    const float* bc   = (const float*)d_in[6];
    const float* w2   = (const float*)d_in[7];
    const float* b2   = (const float*)d_in[8];
    const float* Wi   = (const float*)d_in[9];
    const float* bi   = (const float*)d_in[10];
    const float* Wii  = (const float*)d_in[11];
    const float* bii  = (const float*)d_in[12];
    float* out = (float*)d_out;

    char* ws = (char*)d_ws;
    const size_t XNT_BYTES   = (size_t)B * D * S * 2;        // 50331648
    const size_t STATS_BYTES = (size_t)B * S * 2 * 4;        // 131072
    const size_t C_BYTES     = (size_t)B * D24 * S * 4;      // 4194304 (transposed)
    const size_t WBF_BYTES   = (size_t)2 * S * S * 2;        // 1048576
    const size_t PART_BYTES  = (size_t)B * 2 * 10 * 4;       // 2560
    unsigned short* xnT   = (unsigned short*)ws;
    float*          stat  = (float*)(ws + XNT_BYTES);
    float*          cbufT = (float*)(ws + XNT_BYTES + STATS_BYTES);
    unsigned short* wbf   = (unsigned short*)(ws + XNT_BYTES + STATS_BYTES + C_BYTES);
    float*          part  = (float*)(ws + XNT_BYTES + STATS_BYTES + C_BYTES + WBF_BYTES);
    int*            sel   = (int*)(ws + XNT_BYTES + STATS_BYTES + C_BYTES + WBF_BYTES + PART_BYTES);

    stats_kernel<<<(B * S) / 4, 256, 0, stream>>>(x, stat);
    convw_kernel<<<(2 * S * S) / 1024, 256, 0, stream>>>(Wi, Wii, wbf);
    nt_kernel<<<dim3(D / 64, S / 64, B), 256, 0, stream>>>(x, stat, ln_g, ln_b, xnT, cbufT);
    gateA_kernel<<<B * 2, 256, 0, stream>>>(cbufT, w1, b1, wc, part);
    gateB_kernel<<<1, 64, 0, stream>>>(part, bc, w2, b2, sel);
    gemm_kernel<<<dim3(D / 128, S / 128, B), 256, 0, stream>>>(xnT, wbf, sel, bi, bii, x, out);
}

// Round 4
// 288.035 us; speedup vs baseline: 1.4867x; 1.0611x over previous
//
#include <hip/hip_runtime.h>
#include <hip/hip_bf16.h>
#include <cstddef>

#define B 32
#define S 512
#define D 1536
#define D24 64
#define EPS 1e-5f

typedef float float4v __attribute__((ext_vector_type(4)));
typedef short short8 __attribute__((ext_vector_type(8)));

__device__ __forceinline__ float gelu_exact(float v) {
    return 0.5f * v * (1.0f + erff(v * 0.70710678118654752440f));
}

// tanh-form gelu (epilogue only): max abs err ~1e-3 << 0.164 threshold.
__device__ __forceinline__ float gelu_fast(float v) {
    float u = v * v;
    float z = v * __builtin_fmaf(0.07135481627f, u, 1.5957691216f);
    return v / (1.0f + __expf(-z));
}

__device__ __forceinline__ unsigned short f2bf(float f) {
    union { float f; unsigned u; } x; x.f = f;
    unsigned r = x.u + 0x7fffu + ((x.u >> 16) & 1u);  // RNE
    return (unsigned short)(r >> 16);
}

// ---------------- Kernel 1: fused LN stats + normalize + transpose ----------------
// grid (S/64, B), 256 threads. Pass 1: row stats for 64 rows (HBM read).
// Pass 2: re-read x (L2/L3-warm), normalize, transpose to xnT[b][d][t] bf16,
// plus fp32 cbufT[b][0:64][t] slice for the gate.
__global__ __launch_bounds__(256) void ln_kernel(const float* __restrict__ x,
                                                 const float* __restrict__ ln_g,
                                                 const float* __restrict__ ln_b,
                                                 unsigned short* __restrict__ xnT,
                                                 float* __restrict__ cbufT) {
    const int b  = blockIdx.y;
    const int t0 = blockIdx.x * 64;
    const int tid  = threadIdx.x;
    const int lane = tid & 63;
    const int w    = tid >> 6;

    __shared__ float tile[64][65];
    __shared__ float lmu[64], lrs[64];

    // ---- pass 1: stats ----
    for (int r = 0; r < 16; r++) {
        int row = w * 16 + r;                      // 0..63
        const float4* xr = (const float4*)(x + ((size_t)(b * S + t0 + row)) * D);
        float s1 = 0.f, s2 = 0.f;
#pragma unroll
        for (int j = 0; j < 6; j++) {
            float4 v = xr[lane + j * 64];
            s1 += v.x + v.y + v.z + v.w;
            s2 += v.x * v.x + v.y * v.y + v.z * v.z + v.w * v.w;
        }
#pragma unroll
        for (int off = 32; off > 0; off >>= 1) {
            s1 += __shfl_down(s1, off, 64);
            s2 += __shfl_down(s2, off, 64);
        }
        if (lane == 0) {
            float mu  = s1 * (1.0f / D);
            float var = s2 * (1.0f / D) - mu * mu;
            lmu[row] = mu;
            lrs[row] = rsqrtf(var + EPS);
        }
    }
    __syncthreads();

    // ---- pass 2: 24 tiles of 64x64: normalize + transpose ----
    const int dq = (tid & 15) * 4;
    const int rg = tid >> 4;                       // 0..15
    const int t8  = (tid & 7) * 8;
    const int dr0 = tid >> 3;                      // 0..31

    for (int dt = 0; dt < 24; dt++) {
        const int d0 = dt * 64;
        float4 g4 = *(const float4*)(ln_g + d0 + dq);
        float4 b4 = *(const float4*)(ln_b + d0 + dq);
#pragma unroll
        for (int p = 0; p < 4; p++) {
            int row  = rg + p * 16;
            float mu   = lmu[row];
            float rstd = lrs[row];
            float4 v = *(const float4*)(x + ((size_t)(b * S + t0 + row)) * D + d0 + dq);
            tile[row][dq + 0] = (v.x - mu) * rstd * g4.x + b4.x;
            tile[row][dq + 1] = (v.y - mu) * rstd * g4.y + b4.y;
            tile[row][dq + 2] = (v.z - mu) * rstd * g4.z + b4.z;
            tile[row][dq + 3] = (v.w - mu) * rstd * g4.w + b4.w;
        }
        __syncthreads();
#pragma unroll
        for (int p = 0; p < 2; p++) {
            int drow = dr0 + p * 32;
            float fv[8];
            unsigned short bv[8];
#pragma unroll
            for (int j = 0; j < 8; j++) { fv[j] = tile[t8 + j][drow]; bv[j] = f2bf(fv[j]); }
            *(short8*)(xnT + ((size_t)b * D + d0 + drow) * S + t0 + t8) = *(const short8*)bv;
            if (dt == 0) {
                float* cp = cbufT + ((size_t)b * D24 + drow) * S + t0 + t8;
                *(float4*)(cp + 0) = (float4){fv[0], fv[1], fv[2], fv[3]};
                *(float4*)(cp + 4) = (float4){fv[4], fv[5], fv[6], fv[7]};
            }
        }
        __syncthreads();
    }
}

// ---------------- Kernel 2: convert Wi/Wii to bf16 (vectorized) ----------------
__global__ __launch_bounds__(256) void convw_kernel(const float* __restrict__ Wi,
                                                    const float* __restrict__ Wii,
                                                    unsigned short* __restrict__ wbf) {
    int i = (blockIdx.x * 256 + threadIdx.x) * 4;   // grid covers 2*512*512 floats
    const float* src = (i < S * S) ? (Wi + i) : (Wii + i - S * S);
    float4 v = *(const float4*)src;
    unsigned short o[4] = {f2bf(v.x), f2bf(v.y), f2bf(v.z), f2bf(v.w)};
    *(uint2*)(wbf + i) = *(const uint2*)o;
}

// ---------------- Kernel 3a: gating MLP stage A (coalesced over s) ----------------
__global__ __launch_bounds__(256) void gateA_kernel(const float* __restrict__ cbufT,
                                                    const float* __restrict__ w1,
                                                    const float* __restrict__ b1,
                                                    const float* __restrict__ wc,
                                                    float* __restrict__ partial) {
    const int b  = blockIdx.x >> 1;
    const int sb = blockIdx.x & 1;
    const int tid = threadIdx.x;
    const int s = sb * 256 + tid;
    __shared__ float w1s[D24 * 10];
    __shared__ float wsum[4][10];
    for (int i = tid; i < D24 * 10; i += 256) w1s[i] = w1[i];
    __syncthreads();

    float acc[10];
#pragma unroll
    for (int k = 0; k < 10; k++) acc[k] = b1[k];
    const float* cb = cbufT + (size_t)b * D24 * S + s;
#pragma unroll 8
    for (int i = 0; i < D24; i++) {
        float v = cb[(size_t)i * S];
#pragma unroll
        for (int k = 0; k < 10; k++) acc[k] += v * w1s[i * 10 + k];
    }
    float wcs = wc[s];
#pragma unroll
    for (int k = 0; k < 10; k++) {
        float t = gelu_exact(acc[k]) * wcs;
#pragma unroll
        for (int off = 32; off > 0; off >>= 1) t += __shfl_down(t, off, 64);
        if ((tid & 63) == 0) wsum[tid >> 6][k] = t;
    }
    __syncthreads();
    if (tid < 10)
        partial[blockIdx.x * 10 + tid] =
            wsum[0][tid] + wsum[1][tid] + wsum[2][tid] + wsum[3][tid];
}

// ---------------- Kernel 3b: gating MLP stage B -> sel[b] ----------------
__global__ __launch_bounds__(64) void gateB_kernel(const float* __restrict__ partial,
                                                   const float* __restrict__ bc,
                                                   const float* __restrict__ w2,
                                                   const float* __restrict__ b2,
                                                   int* __restrict__ sel) {
    int b = threadIdx.x;
    if (b < B) {
        float logit = b2[0];
        float bc0 = bc[0];
#pragma unroll
        for (int k = 0; k < 10; k++) {
            float ssum = partial[(b * 2) * 10 + k] + partial[(b * 2 + 1) * 10 + k];
            logit += gelu_exact(ssum + bc0) * w2[k];
        }
        sel[b] = (logit >= 0.f) ? 1 : 0;   // round(sigmoid(x)) == (x >= 0)
    }
}

// ---------------- Kernel 4: main GEMM + bias + residual + gelu ----------------
// out[b,s,d] = gelu( sum_t W[s,t]*xn[b,t,d] + bias[s] + x[b,s,d] )
// BK=64, double-buffered LDS. Prefetch for tile k+1 is issued right after the
// barrier, compute on tile k runs with no dependency on it, and the end-of-iter
// barrier's vmcnt(0) drain lands after the loads had the whole compute phase
// in flight. 16B chunks XOR-swizzled (conflict-free, verified R3).
__global__ __launch_bounds__(256, 2) void gemm_kernel(const unsigned short* __restrict__ xnT,
                                                      const unsigned short* __restrict__ wbf,
                                                      const int* __restrict__ sel,
                                                      const float* __restrict__ bi,
                                                      const float* __restrict__ bii,
                                                      const float* __restrict__ x,
                                                      float* __restrict__ out) {
    const int b  = blockIdx.z;
    const int s0 = blockIdx.y * 128;
    const int d0 = blockIdx.x * 128;
    const int tid  = threadIdx.x;
    const int lane = tid & 63;
    const int wid  = tid >> 6;
    const int wm = (wid & 1) * 64;
    const int wn = (wid >> 1) * 64;
    const int q   = lane >> 4;
    const int r16 = lane & 15;

    const int ssel = sel[b];
    const unsigned short* W = wbf + (size_t)ssel * S * S;
    const float* bias = ssel ? bii : bi;
    const unsigned short* Xb = xnT + (size_t)b * D * S;

    __shared__ __align__(16) unsigned short As[2][128 * 64];  // [row][64k], swizzled chunks
    __shared__ __align__(16) unsigned short Bs[2][128 * 64];

    // stage tile k0 into buffer bf (4 x 256 lane-linear 16B chunks per array)
    auto stage = [&](int k0, int bf) {
#pragma unroll
        for (int i = 0; i < 4; i++) {
            int L = i * 256 + tid;          // 16B-chunk index 0..1023
            int row = L >> 3;               // 0..127
            int sc  = L & 7;                // stored chunk slot
            int c16 = sc ^ (row & 7);       // logical k-chunk in that slot
            const unsigned short* gaA = W  + (size_t)(s0 + row) * S + k0 + c16 * 8;
            const unsigned short* gaB = Xb + (size_t)(d0 + row) * S + k0 + c16 * 8;
            unsigned short* laA = As[bf] + (size_t)(i * 256 + wid * 64) * 8;  // wave-uniform base
            unsigned short* laB = Bs[bf] + (size_t)(i * 256 + wid * 64) * 8;
            __builtin_amdgcn_global_load_lds(
                (const __attribute__((address_space(1))) void*)gaA,
                (__attribute__((address_space(3))) void*)laA, 16, 0, 0);
            __builtin_amdgcn_global_load_lds(
                (const __attribute__((address_space(1))) void*)gaB,
                (__attribute__((address_space(3))) void*)laB, 16, 0, 0);
        }
    };

    float4v acc[4][4];
#pragma unroll
    for (int mi = 0; mi < 4; mi++)
#pragma unroll
        for (int ni = 0; ni < 4; ni++) acc[mi][ni] = (float4v){0.f, 0.f, 0.f, 0.f};

    stage(0, 0);
    __syncthreads();                       // drains tile-0 loads

    for (int it = 0; it < 8; it++) {
        const int cur = it & 1;
        if (it < 7) stage((it + 1) * 64, cur ^ 1);   // fire-and-forget prefetch

        const unsigned short* Ac = As[cur];
        const unsigned short* Bc = Bs[cur];
#pragma unroll
        for (int h = 0; h < 2; h++) {
            short8 af[4], bfr[4];
#pragma unroll
            for (int mi = 0; mi < 4; mi++) {
                int row = wm + mi * 16 + r16;
                af[mi] = *(const short8*)(Ac + row * 64 + (((h << 2) + q) ^ (r16 & 7)) * 8);
            }
#pragma unroll
            for (int ni = 0; ni < 4; ni++) {
                int row = wn + ni * 16 + r16;
                bfr[ni] = *(const short8*)(Bc + row * 64 + (((h << 2) + q) ^ (r16 & 7)) * 8);
            }
#pragma unroll
            for (int mi = 0; mi < 4; mi++)
#pragma unroll
                for (int ni = 0; ni < 4; ni++)
                    acc[mi][ni] = __builtin_amdgcn_mfma_f32_16x16x32_bf16(
                        af[mi], bfr[ni], acc[mi][ni], 0, 0, 0);
        }
        __syncthreads();                   // drains the overlapped prefetch + guards reuse
    }

    // Epilogue: C/D layout col=lane&15, row=(lane>>4)*4+r ; fast gelu
#pragma unroll
    for (int mi = 0; mi < 4; mi++) {
        int srow = s0 + wm + mi * 16 + q * 4;
#pragma unroll
        for (int ni = 0; ni < 4; ni++) {
            int d = d0 + wn + ni * 16 + r16;
#pragma unroll
            for (int r = 0; r < 4; r++) {
                int ss = srow + r;
                size_t gi = ((size_t)b * S + ss) * D + d;
                float v = acc[mi][ni][r] + bias[ss] + x[gi];
                out[gi] = gelu_fast(v);
            }
        }
    }
}

extern "C" void kernel_launch(void* const* d_in, const int* in_sizes, int n_in,
                              void* d_out, int out_size, void* d_ws, size_t ws_size,
                              hipStream_t stream) {
    const float* x    = (const float*)d_in[0];
    const float* ln_g = (const float*)d_in[1];
    const float* ln_b = (const float*)d_in[2];
    const float* w1   = (const float*)d_in[3];
    const float* b1   = (const float*)d_in[4];
    const float* wc   = (const float*)d_in[5];
    const float* bc   = (const float*)d_in[6];
    const float* w2   = (const float*)d_in[7];
    const float* b2   = (const float*)d_in[8];
    const float* Wi   = (const float*)d_in[9];
    const float* bi   = (const float*)d_in[10];
    const float* Wii  = (const float*)d_in[11];
    const float* bii  = (const float*)d_in[12];
    float* out = (float*)d_out;

    char* ws = (char*)d_ws;
    const size_t XNT_BYTES   = (size_t)B * D * S * 2;        // 50331648
    const size_t C_BYTES     = (size_t)B * D24 * S * 4;      // 4194304 (transposed)
    const size_t WBF_BYTES   = (size_t)2 * S * S * 2;        // 1048576
    const size_t PART_BYTES  = (size_t)B * 2 * 10 * 4;       // 2560
    unsigned short* xnT   = (unsigned short*)ws;
    float*          cbufT = (float*)(ws + XNT_BYTES);
    unsigned short* wbf   = (unsigned short*)(ws + XNT_BYTES + C_BYTES);
    float*          part  = (float*)(ws + XNT_BYTES + C_BYTES + WBF_BYTES);
    int*            sel   = (int*)(ws + XNT_BYTES + C_BYTES + WBF_BYTES + PART_BYTES);

    ln_kernel<<<dim3(S / 64, B), 256, 0, stream>>>(x, ln_g, ln_b, xnT, cbufT);
    convw_kernel<<<(2 * S * S) / 1024, 256, 0, stream>>>(Wi, Wii, wbf);
    gateA_kernel<<<B * 2, 256, 0, stream>>>(cbufT, w1, b1, wc, part);
    gateB_kernel<<<1, 64, 0, stream>>>(part, bc, w2, b2, sel);
    gemm_kernel<<<dim3(D / 128, S / 128, B), 256, 0, stream>>>(xnT, wbf, sel, bi, bii, x, out);
}